// Round 1
// baseline (121.423 us; speedup 1.0000x reference)
//
#include <hip/hip_runtime.h>
#include <hip/hip_bf16.h>
#include <stdint.h>

#define Bb 32
#define Ll 512
#define Dd 768
#define Hh 100
#define Cc 45
#define CP 48   // padded column count (3 x 16)
#define MROWS (Bb * Ll)  // 16384

typedef __attribute__((ext_vector_type(8))) short short8;
typedef __attribute__((ext_vector_type(4))) float f32x4;

__device__ __forceinline__ unsigned short f2bf_rne(float v) {
    uint32_t u = __float_as_uint(v);
    return (unsigned short)((u + 0x7fffu + ((u >> 16) & 1u)) >> 16);
}

// ---------------- Kernel A: fold the two linear layers ----------------
// Wc[c][d] = sum_h W2[c][h] * W1[h][d]   (bf16, rows 45..47 zero)
// bc[c]    = sum_h W2[c][h] * b1[h] + b2[c]
__global__ void prep_wc(const float* __restrict__ W1, const float* __restrict__ b1,
                        const float* __restrict__ W2, const float* __restrict__ b2,
                        unsigned short* __restrict__ Wc, float* __restrict__ bc) {
    int c = blockIdx.x;      // 0..47
    int t = threadIdx.x;     // 0..255
    if (c >= Cc) {
        for (int i = t; i < Dd; i += 256) Wc[c * Dd + i] = 0;
        if (t == 0) bc[c] = 0.f;
        return;
    }
    float a0 = 0.f, a1 = 0.f, a2 = 0.f;
    const int d0 = t, d1 = t + 256, d2 = t + 512;
    for (int h = 0; h < Hh; ++h) {
        float w2 = W2[c * Hh + h];
        a0 += w2 * W1[h * Dd + d0];
        a1 += w2 * W1[h * Dd + d1];
        a2 += w2 * W1[h * Dd + d2];
    }
    Wc[c * Dd + d0] = f2bf_rne(a0);
    Wc[c * Dd + d1] = f2bf_rne(a1);
    Wc[c * Dd + d2] = f2bf_rne(a2);
    if (t == 0) {
        float s = b2[c];
        for (int h = 0; h < Hh; ++h) s += W2[c * Hh + h] * b1[h];
        bc[c] = s;
    }
}

// ---------------- Kernel B: per-batch compaction gather index ----------------
// gather[b*L + p] = absolute source row (b*L + l) of p-th valid token, else -1
__global__ void prep_gather(const int* __restrict__ valid, int* __restrict__ gather) {
    int b = blockIdx.x;    // 0..31
    int t = threadIdx.x;   // 0..511
    __shared__ int s[Ll];
    int v = (valid[b * Ll + t] == 1) ? 1 : 0;
    s[t] = v;
    gather[b * Ll + t] = -1;
    __syncthreads();
    for (int off = 1; off < Ll; off <<= 1) {
        int x = (t >= off) ? s[t - off] : 0;
        __syncthreads();
        s[t] += x;
        __syncthreads();
    }
    if (v) gather[b * Ll + (s[t] - 1)] = b * Ll + t;
}

// ---------------- Kernel C: gathered skinny GEMM ----------------
// out[16384, 45] = gather(x) @ Wc^T + bc   via mfma_f32_16x16x32_bf16
// Each wave: 16 rows x 48 cols (3 accumulators), K=768 in 24 steps of 32.
__global__ __launch_bounds__(256) void gemm_out(
    const float* __restrict__ x,             // (16384, 768) fp32
    const unsigned short* __restrict__ Wc,   // (48, 768) bf16
    const float* __restrict__ bc,            // (48)
    const int* __restrict__ gather,          // (16384)
    float* __restrict__ out)                 // (16384, 45)
{
    const int wave = threadIdx.x >> 6;
    const int lane = threadIdx.x & 63;
    const int quad = lane >> 4;
    const int nn   = lane & 15;
    const int rowbase = (blockIdx.x * 4 + wave) * 16;

    // A-frag: row m = lane&15, k = quad*8 + j (+ 32*ks)
    const int src = gather[rowbase + nn];
    const float* xp = x + (long)(src >= 0 ? src : 0) * Dd + quad * 8;

    // B-frag: col n = lane&15, k = quad*8 + j (+ 32*ks); B[k][n] = Wc[n][k]
    const unsigned short* bp0 = Wc + (0 * 16 + nn) * Dd + quad * 8;
    const unsigned short* bp1 = Wc + (1 * 16 + nn) * Dd + quad * 8;
    const unsigned short* bp2 = Wc + (2 * 16 + nn) * Dd + quad * 8;

    f32x4 acc0 = {0.f, 0.f, 0.f, 0.f};
    f32x4 acc1 = {0.f, 0.f, 0.f, 0.f};
    f32x4 acc2 = {0.f, 0.f, 0.f, 0.f};

    #pragma unroll 6
    for (int ks = 0; ks < 24; ++ks) {
        union { short8 s; uint32_t u[4]; } A;
        A.u[0] = 0; A.u[1] = 0; A.u[2] = 0; A.u[3] = 0;
        if (src >= 0) {
            f32x4 xa = *(const f32x4*)(xp + ks * 32);
            f32x4 xb = *(const f32x4*)(xp + ks * 32 + 4);
            // truncate fp32 -> bf16, pack pairs (low=even elem, high=odd elem)
            A.u[0] = (__float_as_uint(xa.x) >> 16) | (__float_as_uint(xa.y) & 0xffff0000u);
            A.u[1] = (__float_as_uint(xa.z) >> 16) | (__float_as_uint(xa.w) & 0xffff0000u);
            A.u[2] = (__float_as_uint(xb.x) >> 16) | (__float_as_uint(xb.y) & 0xffff0000u);
            A.u[3] = (__float_as_uint(xb.z) >> 16) | (__float_as_uint(xb.w) & 0xffff0000u);
        }
        short8 b0 = *(const short8*)(bp0 + ks * 32);
        short8 b1v = *(const short8*)(bp1 + ks * 32);
        short8 b2v = *(const short8*)(bp2 + ks * 32);
        acc0 = __builtin_amdgcn_mfma_f32_16x16x32_bf16(A.s, b0,  acc0, 0, 0, 0);
        acc1 = __builtin_amdgcn_mfma_f32_16x16x32_bf16(A.s, b1v, acc1, 0, 0, 0);
        acc2 = __builtin_amdgcn_mfma_f32_16x16x32_bf16(A.s, b2v, acc2, 0, 0, 0);
    }

    // Epilogue. C/D layout: col = lane&15, row = quad*4 + reg.
    #pragma unroll
    for (int ct = 0; ct < 3; ++ct) {
        int col = ct * 16 + nn;
        if (col < Cc) {
            float bcv = bc[col];
            f32x4 acc = (ct == 0) ? acc0 : ((ct == 1) ? acc1 : acc2);
            #pragma unroll
            for (int r = 0; r < 4; ++r) {
                int row = rowbase + quad * 4 + r;
                out[row * Cc + col] = acc[r] + bcv;
            }
        }
    }
}

extern "C" void kernel_launch(void* const* d_in, const int* in_sizes, int n_in,
                              void* d_out, int out_size, void* d_ws, size_t ws_size,
                              hipStream_t stream) {
    const float* seq   = (const float*)d_in[0];  // (32,512,768) fp32
    const int*   valid = (const int*)d_in[1];    // (32,512) int32
    const float* W1    = (const float*)d_in[2];  // (100,768)
    const float* b1    = (const float*)d_in[3];  // (100)
    const float* W2    = (const float*)d_in[4];  // (45,100)
    const float* b2    = (const float*)d_in[5];  // (45)
    float* out = (float*)d_out;                  // (16384,45)

    // Workspace layout
    unsigned short* Wc = (unsigned short*)d_ws;                    // 48*768*2 = 73728 B
    float* bc          = (float*)((char*)d_ws + 73728);            // 48*4 = 192 B
    int* gather        = (int*)((char*)d_ws + 73728 + 192);        // 16384*4 B

    prep_wc<<<CP, 256, 0, stream>>>(W1, b1, W2, b2, Wc, bc);
    prep_gather<<<Bb, Ll, 0, stream>>>(valid, gather);
    gemm_out<<<MROWS / 64, 256, 0, stream>>>(seq, Wc, bc, gather, out);
}

// Round 2
// 113.725 us; speedup vs baseline: 1.0677x; 1.0677x over previous
//
#include <hip/hip_runtime.h>
#include <hip/hip_bf16.h>
#include <stdint.h>

#define Bb 32
#define Ll 512
#define Dd 768
#define Hh 100
#define Cc 45
#define CP 48            // padded column count (3 x 16)
#define MROWS (Bb * Ll)  // 16384

typedef __attribute__((ext_vector_type(8))) short short8;
typedef __attribute__((ext_vector_type(4))) float f32x4;

__device__ __forceinline__ unsigned short f2bf_rne(float v) {
    uint32_t u = __float_as_uint(v);
    return (unsigned short)((u + 0x7fffu + ((u >> 16) & 1u)) >> 16);
}

// ---------------- Kernel A: fold the two linear layers ----------------
// Wc[c][d] = sum_h W2[c][h] * W1[h][d]   (bf16 RNE, rows 45..47 zero)
// bc[c]    = sum_h W2[c][h] * b1[h] + b2[c]
// grid: 48 cols x 3 d-chunks = 144 blocks, 256 threads (coalesced W1 reads)
__global__ void prep_wc(const float* __restrict__ W1, const float* __restrict__ b1,
                        const float* __restrict__ W2, const float* __restrict__ b2,
                        unsigned short* __restrict__ Wc, float* __restrict__ bc) {
    const int c     = blockIdx.x / 3;
    const int chunk = blockIdx.x % 3;
    const int t     = threadIdx.x;
    const int d     = chunk * 256 + t;
    if (c >= Cc) {
        Wc[c * Dd + d] = 0;
    } else {
        float a = 0.f;
        const float* w1p = W1 + d;
        const float* w2p = W2 + c * Hh;
        #pragma unroll 4
        for (int h = 0; h < Hh; ++h) a += w2p[h] * w1p[h * Dd];
        Wc[c * Dd + d] = f2bf_rne(a);
    }
    if (blockIdx.x == 0 && t < CP) {
        float s = (t < Cc) ? b2[t] : 0.f;
        if (t < Cc)
            for (int h = 0; h < Hh; ++h) s += W2[t * Hh + h] * b1[h];
        bc[t] = s;
    }
}

// ---------------- Kernel B: fused compaction-scan + skinny GEMM ----------------
// out[16384, 45] = compact(x) @ Wc^T + bc   via mfma_f32_16x16x32_bf16
// Block = 256 threads (4 waves) handles 16 compacted rows of one batch.
// Wave w computes the K-slice [w*192, (w+1)*192); partials LDS-reduced.
__global__ __launch_bounds__(256, 4) void gemm_out(
    const float* __restrict__ x,             // (16384, 768) fp32
    const int* __restrict__ valid,           // (32, 512)
    const unsigned short* __restrict__ Wc,   // (48, 768) bf16
    const float* __restrict__ bc,            // (48)
    float* __restrict__ out)                 // (16384, 45)
{
    __shared__ int   g[Ll];          // compacted pos -> source l (or -1)
    __shared__ int   wsum[4];
    __shared__ float red[4][12][64]; // [wave][ct*4+r][lane]

    const int t    = threadIdx.x;
    const int wave = t >> 6;
    const int lane = t & 63;
    const int quad = lane >> 4;
    const int nn   = lane & 15;

    const int rowbase = blockIdx.x * 16;      // compacted row base (global)
    const int b       = rowbase >> 9;         // batch
    const int p0      = rowbase & (Ll - 1);   // position base within batch

    // ---- in-block stable compaction scan of valid[b][0..511] ----
    g[t] = -1; g[t + 256] = -1;
    int2 vv = ((const int2*)(valid + b * Ll))[t];   // elements 2t, 2t+1
    int v0 = (vv.x == 1), v1 = (vv.y == 1);
    int ps = v0 + v1;
    __syncthreads();                 // g init visible before scatter
    // wave-inclusive scan of ps
    int incl = ps;
    #pragma unroll
    for (int d = 1; d < 64; d <<= 1) {
        int n = __shfl_up(incl, d, 64);
        if (lane >= d) incl += n;
    }
    if (lane == 63) wsum[wave] = incl;
    __syncthreads();
    int woff = 0;
    #pragma unroll
    for (int w = 0; w < 4; ++w) woff += (w < wave) ? wsum[w] : 0;
    int e = woff + incl - ps;        // exclusive prefix for element 2t
    if (v0) g[e] = 2 * t;
    if (v1) g[e + v0] = 2 * t + 1;
    __syncthreads();

    // ---- fragment pointers ----
    const int srcl = g[p0 + nn];                    // source l within batch, or -1
    const int src  = (srcl >= 0) ? (b * Ll + srcl) : -1;
    const float* xp = x + (long)(src >= 0 ? src : 0) * Dd + wave * 192 + quad * 8;
    const unsigned short* bp = Wc + nn * Dd + wave * 192 + quad * 8;

    f32x4 acc0 = {0.f, 0.f, 0.f, 0.f};
    f32x4 acc1 = {0.f, 0.f, 0.f, 0.f};
    f32x4 acc2 = {0.f, 0.f, 0.f, 0.f};

    #pragma unroll
    for (int ks = 0; ks < 6; ++ks) {
        union { short8 s; uint32_t u[4]; } A;
        A.u[0] = 0; A.u[1] = 0; A.u[2] = 0; A.u[3] = 0;
        if (src >= 0) {
            f32x4 xa = *(const f32x4*)(xp + ks * 32);
            f32x4 xb = *(const f32x4*)(xp + ks * 32 + 4);
            A.u[0] = (__float_as_uint(xa.x) >> 16) | (__float_as_uint(xa.y) & 0xffff0000u);
            A.u[1] = (__float_as_uint(xa.z) >> 16) | (__float_as_uint(xa.w) & 0xffff0000u);
            A.u[2] = (__float_as_uint(xb.x) >> 16) | (__float_as_uint(xb.y) & 0xffff0000u);
            A.u[3] = (__float_as_uint(xb.z) >> 16) | (__float_as_uint(xb.w) & 0xffff0000u);
        }
        short8 b0 = *(const short8*)(bp + 0 * 16 * Dd + ks * 32);
        short8 b1v = *(const short8*)(bp + 1 * 16 * Dd + ks * 32);
        short8 b2v = *(const short8*)(bp + 2 * 16 * Dd + ks * 32);
        acc0 = __builtin_amdgcn_mfma_f32_16x16x32_bf16(A.s, b0,  acc0, 0, 0, 0);
        acc1 = __builtin_amdgcn_mfma_f32_16x16x32_bf16(A.s, b1v, acc1, 0, 0, 0);
        acc2 = __builtin_amdgcn_mfma_f32_16x16x32_bf16(A.s, b2v, acc2, 0, 0, 0);
    }

    // ---- write partials, reduce across the 4 K-slices ----
    #pragma unroll
    for (int r = 0; r < 4; ++r) {
        red[wave][0 * 4 + r][lane] = acc0[r];
        red[wave][1 * 4 + r][lane] = acc1[r];
        red[wave][2 * 4 + r][lane] = acc2[r];
    }
    __syncthreads();

    #pragma unroll
    for (int oo = 0; oo < 3; ++oo) {
        int o = t + oo * 256;            // 0..767
        int j = o >> 6, l = o & 63;
        float s = red[0][j][l] + red[1][j][l] + red[2][j][l] + red[3][j][l];
        int q = l >> 4, n2 = l & 15;
        int ct = j >> 2, r = j & 3;
        int col = ct * 16 + n2;
        if (col < Cc) {
            int row = rowbase + q * 4 + r;
            out[row * Cc + col] = s + bc[col];
        }
    }
}

extern "C" void kernel_launch(void* const* d_in, const int* in_sizes, int n_in,
                              void* d_out, int out_size, void* d_ws, size_t ws_size,
                              hipStream_t stream) {
    const float* seq   = (const float*)d_in[0];  // (32,512,768) fp32
    const int*   valid = (const int*)d_in[1];    // (32,512) int32
    const float* W1    = (const float*)d_in[2];  // (100,768)
    const float* b1    = (const float*)d_in[3];  // (100)
    const float* W2    = (const float*)d_in[4];  // (45,100)
    const float* b2    = (const float*)d_in[5];  // (45)
    float* out = (float*)d_out;                  // (16384,45)

    unsigned short* Wc = (unsigned short*)d_ws;             // 48*768*2 = 73728 B
    float* bc          = (float*)((char*)d_ws + 73728);     // 48*4 B

    prep_wc<<<CP * 3, 256, 0, stream>>>(W1, b1, W2, b2, Wc, bc);
    gemm_out<<<MROWS / 16, 256, 0, stream>>>(seq, valid, Wc, bc, out);
}

// Round 3
// 105.193 us; speedup vs baseline: 1.1543x; 1.0811x over previous
//
#include <hip/hip_runtime.h>
#include <hip/hip_bf16.h>
#include <stdint.h>

#define Bb 32
#define Ll 512
#define Dd 768
#define Hh 100
#define Cc 45
#define CP 48            // padded column count (3 x 16)
#define MROWS (Bb * Ll)  // 16384
#define WC_BLOCKS 72     // 72*512 = 48*768 outputs

typedef __attribute__((ext_vector_type(8))) short short8;
typedef __attribute__((ext_vector_type(4))) float f32x4;

__device__ __forceinline__ unsigned short f2bf_rne(float v) {
    uint32_t u = __float_as_uint(v);
    return (unsigned short)((u + 0x7fffu + ((u >> 16) & 1u)) >> 16);
}

// ---------------- Kernel A: fused prep ----------------
// blocks 0..71   : Wc[c][d] = sum_h W2[c][h]*W1[h][d]  (bf16 RNE, rows 45..47 = 0)
// blocks 72..103 : gather[b][p] = source l of p-th valid token in batch b, else -1
// block  104     : bc[c] = W2[c]·b1 + b2[c]
__global__ __launch_bounds__(512) void prep(
    const float* __restrict__ W1, const float* __restrict__ b1,
    const float* __restrict__ W2, const float* __restrict__ b2,
    const int* __restrict__ valid,
    unsigned short* __restrict__ Wc, float* __restrict__ bc,
    int* __restrict__ gather)
{
    const int t = threadIdx.x;

    if (blockIdx.x < WC_BLOCKS) {
        // ---- Wc fold: one output per thread ----
        const int o = blockIdx.x * 512 + t;       // 0..36863
        const int c = o / Dd;
        const int d = o - c * Dd;
        if (c >= Cc) { Wc[o] = 0; return; }
        const float* w1 = W1 + d;
        const float* w2 = W2 + c * Hh;
        float a0 = 0.f, a1 = 0.f, a2 = 0.f, a3 = 0.f;
        #pragma unroll
        for (int h = 0; h < Hh; h += 4) {
            a0 += w2[h + 0] * w1[(h + 0) * Dd];
            a1 += w2[h + 1] * w1[(h + 1) * Dd];
            a2 += w2[h + 2] * w1[(h + 2) * Dd];
            a3 += w2[h + 3] * w1[(h + 3) * Dd];
        }
        Wc[o] = f2bf_rne((a0 + a1) + (a2 + a3));
        return;
    }

    if (blockIdx.x < WC_BLOCKS + Bb) {
        // ---- compaction scan for batch b ----
        const int b    = blockIdx.x - WC_BLOCKS;
        const int wave = t >> 6;
        const int lane = t & 63;
        __shared__ int wsum[8];
        int v = (valid[b * Ll + t] == 1) ? 1 : 0;
        gather[b * Ll + t] = -1;
        int incl = v;
        #pragma unroll
        for (int d = 1; d < 64; d <<= 1) {
            int n = __shfl_up(incl, d, 64);
            if (lane >= d) incl += n;
        }
        if (lane == 63) wsum[wave] = incl;
        __syncthreads();   // orders gather init before scatter, publishes wsum
        int woff = 0;
        #pragma unroll
        for (int w = 0; w < 8; ++w) woff += (w < wave) ? wsum[w] : 0;
        if (v) gather[b * Ll + woff + incl - 1] = t;
        return;
    }

    // ---- bc ----
    if (t < CP) {
        float s = 0.f;
        if (t < Cc) {
            s = b2[t];
            for (int h = 0; h < Hh; ++h) s += W2[t * Hh + h] * b1[h];
        }
        bc[t] = s;
    }
}

// ---------------- Kernel B: gathered skinny GEMM ----------------
// out[16384, 45] = compact(x) @ Wc^T + bc   via mfma_f32_16x16x32_bf16
// Block = 256 threads (4 waves) handles 16 compacted rows of one batch.
// Wave w computes K-slice [w*192, (w+1)*192); partials LDS-reduced.
__global__ __launch_bounds__(256, 4) void gemm_out(
    const float* __restrict__ x,             // (16384, 768) fp32
    const unsigned short* __restrict__ Wc,   // (48, 768) bf16
    const float* __restrict__ bc,            // (48)
    const int* __restrict__ gather,          // (32, 512)
    float* __restrict__ out)                 // (16384, 45)
{
    __shared__ float red[4][12][64]; // [wave][ct*4+r][lane]

    const int t    = threadIdx.x;
    const int wave = t >> 6;
    const int lane = t & 63;
    const int quad = lane >> 4;
    const int nn   = lane & 15;

    const int rowbase = blockIdx.x * 16;      // compacted row base (global)
    const int b       = rowbase >> 9;         // batch
    const int p0      = rowbase & (Ll - 1);   // position base within batch

    const int srcl = gather[rowbase + nn];    // source l within batch, or -1
    const int src  = (srcl >= 0) ? (b * Ll + srcl) : -1;
    const float* xp = x + (long)(src >= 0 ? src : 0) * Dd + wave * 192 + quad * 8;
    const unsigned short* bp = Wc + nn * Dd + wave * 192 + quad * 8;

    f32x4 acc0 = {0.f, 0.f, 0.f, 0.f};
    f32x4 acc1 = {0.f, 0.f, 0.f, 0.f};
    f32x4 acc2 = {0.f, 0.f, 0.f, 0.f};

    #pragma unroll
    for (int ks = 0; ks < 6; ++ks) {
        union { short8 s; uint32_t u[4]; } A;
        A.u[0] = 0; A.u[1] = 0; A.u[2] = 0; A.u[3] = 0;
        if (src >= 0) {
            f32x4 xa = *(const f32x4*)(xp + ks * 32);
            f32x4 xb = *(const f32x4*)(xp + ks * 32 + 4);
            A.u[0] = (__float_as_uint(xa.x) >> 16) | (__float_as_uint(xa.y) & 0xffff0000u);
            A.u[1] = (__float_as_uint(xa.z) >> 16) | (__float_as_uint(xa.w) & 0xffff0000u);
            A.u[2] = (__float_as_uint(xb.x) >> 16) | (__float_as_uint(xb.y) & 0xffff0000u);
            A.u[3] = (__float_as_uint(xb.z) >> 16) | (__float_as_uint(xb.w) & 0xffff0000u);
        }
        short8 b0  = *(const short8*)(bp + 0 * 16 * Dd + ks * 32);
        short8 b1v = *(const short8*)(bp + 1 * 16 * Dd + ks * 32);
        short8 b2v = *(const short8*)(bp + 2 * 16 * Dd + ks * 32);
        acc0 = __builtin_amdgcn_mfma_f32_16x16x32_bf16(A.s, b0,  acc0, 0, 0, 0);
        acc1 = __builtin_amdgcn_mfma_f32_16x16x32_bf16(A.s, b1v, acc1, 0, 0, 0);
        acc2 = __builtin_amdgcn_mfma_f32_16x16x32_bf16(A.s, b2v, acc2, 0, 0, 0);
    }

    // ---- write partials, reduce across the 4 K-slices ----
    #pragma unroll
    for (int r = 0; r < 4; ++r) {
        red[wave][0 * 4 + r][lane] = acc0[r];
        red[wave][1 * 4 + r][lane] = acc1[r];
        red[wave][2 * 4 + r][lane] = acc2[r];
    }
    __syncthreads();

    #pragma unroll
    for (int oo = 0; oo < 3; ++oo) {
        int o = t + oo * 256;            // 0..767
        int j = o >> 6, l = o & 63;
        float s = red[0][j][l] + red[1][j][l] + red[2][j][l] + red[3][j][l];
        int q = l >> 4, n2 = l & 15;
        int ct = j >> 2, r = j & 3;
        int col = ct * 16 + n2;
        if (col < Cc) {
            int row = rowbase + q * 4 + r;
            out[row * Cc + col] = s + bc[col];
        }
    }
}

extern "C" void kernel_launch(void* const* d_in, const int* in_sizes, int n_in,
                              void* d_out, int out_size, void* d_ws, size_t ws_size,
                              hipStream_t stream) {
    const float* seq   = (const float*)d_in[0];  // (32,512,768) fp32
    const int*   valid = (const int*)d_in[1];    // (32,512) int32
    const float* W1    = (const float*)d_in[2];  // (100,768)
    const float* b1    = (const float*)d_in[3];  // (100)
    const float* W2    = (const float*)d_in[4];  // (45,100)
    const float* b2    = (const float*)d_in[5];  // (45)
    float* out = (float*)d_out;                  // (16384,45)

    unsigned short* Wc = (unsigned short*)d_ws;                 // 48*768*2 = 73728 B
    float* bc          = (float*)((char*)d_ws + 73728);         // 48*4 B
    int* gather        = (int*)((char*)d_ws + 73728 + 256);     // 32*512*4 B

    prep<<<WC_BLOCKS + Bb + 1, 512, 0, stream>>>(W1, b1, W2, b2, valid, Wc, bc, gather);
    gemm_out<<<MROWS / 16, 256, 0, stream>>>(seq, Wc, bc, gather, out);
}